// Round 4
// baseline (106.685 us; speedup 1.0000x reference)
//
#include <hip/hip_runtime.h>
#include <math.h>

typedef unsigned int uint32;
typedef __bf16 bf16x8 __attribute__((ext_vector_type(8)));
typedef float f32x16 __attribute__((ext_vector_type(16)));

#define BROWS 8192
#define WDIM 256
#define NT 3              // 128x128 tile pairs: t0=(0,0), t1=(0,1), t2=(1,1)
#define CHUNKS 16         // 16 * 512 rows = 8192
#define RPB 512           // rows per block
#define NSTAGE 4          // 4 x 128-row LDS stages
#define TILE_ELEMS 16384
#define GRID_BLKS (NT * CHUNKS)   // 48 blocks, trivially co-resident

// ws float layout (all ATOMIC-accessed, zeroed in-kernel each launch):
// [0 .. 49151]       G tiles f32: t*16384 + row*128 + col   (3 x 128x128)
// [49152 .. 49407]   colsum f32 [256]
#define WS_G 0
#define WS_CS (NT * TILE_ELEMS)
#define WS_NATOM (WS_CS + WDIM)          // 49408 floats
#define ZSLICE 1030                      // ceil(49408/48)

// Monotonic generation counters (device globals: ws is re-poisoned every
// iteration). +GRID_BLKS per launch; target = next multiple -> no reset
// needed across graph replays.
__device__ unsigned g_zeroed = 0;
__device__ unsigned g_done = 0;

__device__ __forceinline__ uint32 pack2bf(float lo, float hi) {
    uint32 a = __float_as_uint(lo), b = __float_as_uint(hi);
    a = (a + 0x7FFFu + ((a >> 16) & 1u)) >> 16;   // RNE fp32->bf16
    b = (b + 0x7FFFu + ((b >> 16) & 1u)) >> 16;
    return (a & 0xFFFFu) | (b << 16);
}
__device__ __forceinline__ float bflo(uint32 v) { return __uint_as_float(v << 16); }
__device__ __forceinline__ float bfhi(uint32 v) { return __uint_as_float(v & 0xFFFF0000u); }

// LDS layout: U[col][krp] (krp = k/2, 64 dwords per col), 16B-group XOR swizzle.
__device__ __forceinline__ int uswz(int col, int krp) {
    return col * 64 + ((((krp >> 2) ^ (col & 15)) << 2) | (krp & 3));
}

__global__ __launch_bounds__(256)
void corr_onepass(const float* __restrict__ E, float* __restrict__ ws,
                  float* __restrict__ out) {
    __shared__ uint32 U[WDIM * 64];            // 64 KB
    __shared__ float red[4];
    __shared__ int amFinal;
    const int t = blockIdx.x, c = blockIdx.y;
    const int tid = threadIdx.x;
    const int bid = c * NT + t;

    // ---- zero my disjoint slice of the poisoned atomic region ----
    // atomicExch lands at the coherent point, so later cross-XCD atomicAdds
    // see the zeros (proven in round 3).
    #pragma unroll
    for (int k = 0; k < 5; ++k) {
        const int r = k * 256 + tid;
        const int e = bid * ZSLICE + r;
        if (r < ZSLICE && e < WS_NATOM) atomicExch(&ws[e], 0.0f);
    }
    __syncthreads();                           // drains vmcnt: zeros complete
    unsigned ztarget = 0;
    if (tid == 0) {
        const unsigned zo = __hip_atomic_fetch_add(
            &g_zeroed, 1u, __ATOMIC_RELAXED, __HIP_MEMORY_SCOPE_AGENT);
        ztarget = zo - (zo % GRID_BLKS) + GRID_BLKS;
    }

    // ---------------- phase A: 4 stages of load+cast+MFMA ----------------
    const int ncg = (t == 1) ? 4 : 2;          // 64-col groups per stage
    const int ncgsh = (t == 1) ? 2 : 1;
    const int gcol0 = (t == 2) ? 128 : 0;      // global col of U local col 0
    const int row0 = c * RPB;
    const int c4 = tid & 15, rp = tid >> 4;
    const int w = tid >> 6, l = tid & 63, lm = l & 31;
    const int bBase = (t == 1) ? 128 : 0;
    const int colA = w * 32 + lm;

    float csum = 0.f;                          // t==1 colsum over 512 rows
    f32x16 acc[4];
    #pragma unroll
    for (int n = 0; n < 4; ++n)
        #pragma unroll
        for (int r = 0; r < 16; ++r) acc[n][r] = 0.f;

#define ISSUE(IT, FA, FB) do {                                                 \
    const int sc_ = (IT) >> ncgsh, cg_ = (IT) & (ncg - 1);                     \
    const float* Eb_ = E + (size_t)(row0 + sc_ * 128) * WDIM + gcol0 + cg_ * 64;\
    _Pragma("unroll")                                                          \
    for (int p = 0; p < 4; ++p) {                                              \
        const int r0_ = 2 * (rp + 16 * p);                                     \
        FA[p] = *(const float4*)(Eb_ + (size_t)r0_ * WDIM + c4 * 4);           \
        FB[p] = *(const float4*)(Eb_ + (size_t)(r0_ + 1) * WDIM + c4 * 4);     \
    }                                                                          \
} while (0)

#define CONSUME(IT, FA, FB) do {                                               \
    const int cg_ = (IT) & (ncg - 1);                                          \
    const int colb_ = cg_ * 64 + c4 * 4;                                       \
    _Pragma("unroll")                                                          \
    for (int p = 0; p < 4; ++p) {                                              \
        const int krp_ = rp + 16 * p;                                          \
        U[uswz(colb_ + 0, krp_)] = pack2bf(FA[p].x, FB[p].x);                  \
        U[uswz(colb_ + 1, krp_)] = pack2bf(FA[p].y, FB[p].y);                  \
        U[uswz(colb_ + 2, krp_)] = pack2bf(FA[p].z, FB[p].z);                  \
        U[uswz(colb_ + 3, krp_)] = pack2bf(FA[p].w, FB[p].w);                  \
    }                                                                          \
    if (cg_ == ncg - 1) {                                                      \
        __syncthreads();                                                       \
        if (t == 1) {                                                          \
            _Pragma("unroll")                                                  \
            for (int g = 0; g < 16; ++g) {                                     \
                const uint4 v = *(const uint4*)&U[tid * 64 + ((g ^ (tid & 15)) << 2)]; \
                csum += bflo(v.x) + bfhi(v.x) + bflo(v.y) + bfhi(v.y)          \
                      + bflo(v.z) + bfhi(v.z) + bflo(v.w) + bfhi(v.w);         \
            }                                                                  \
        }                                                                      \
        _Pragma("unroll")                                                      \
        for (int s8 = 0; s8 < 8; ++s8) {                                       \
            const int grp = 2 * s8 + (l >> 5);                                 \
            const bf16x8 a = *(const bf16x8*)&U[colA * 64 + ((grp ^ (colA & 15)) << 2)]; \
            _Pragma("unroll")                                                  \
            for (int n = 0; n < 4; ++n) {                                      \
                const int colB = bBase + n * 32 + lm;                          \
                const bf16x8 b = *(const bf16x8*)&U[colB * 64 + ((grp ^ (colB & 15)) << 2)]; \
                acc[n] = __builtin_amdgcn_mfma_f32_32x32x16_bf16(a, b, acc[n], 0, 0, 0); \
            }                                                                  \
        }                                                                      \
        __syncthreads();                                                       \
    }                                                                          \
} while (0)

    // 2-deep register prefetch: HBM latency of the next cg-load hides under
    // LDS-write / barriers / MFMA of the current one.
    float4 Afa[4], Afb[4], Bfa[4], Bfb[4];
    const int iters = NSTAGE * ncg;            // 8 or 16, always even
    ISSUE(0, Afa, Afb);
    for (int it = 0; it < iters; it += 2) {
        ISSUE(it + 1, Bfa, Bfb);
        CONSUME(it, Afa, Afb);
        if (it + 2 < iters) ISSUE(it + 2, Afa, Afb);
        CONSUME(it + 1, Bfa, Bfb);
    }

    // ---- wait until ALL blocks' zeros landed (expected zero spin) ----
    if (tid == 0) {
        while (__hip_atomic_load(&g_zeroed, __ATOMIC_RELAXED,
                                 __HIP_MEMORY_SCOPE_AGENT) < ztarget)
            __builtin_amdgcn_s_sleep(2);
    }
    __syncthreads();

    // ---- publish: f32 atomicAdd partial gram + colsum ----
    // Contending blocks (same t) are de-phased by c&3 via compile-time
    // rotation (keeps acc[n][r] statically indexed).
    // C/D layout (m74/m101): col = lane&31, row = (r&3)+8*(r>>2)+4*(lane>>5)
    float* Gt = ws + WS_G + t * TILE_ELEMS;
    const int rbase = 32 * w + 4 * (l >> 5);
#define PUBROT(RO)                                                             \
    _Pragma("unroll")                                                          \
    for (int nn = 0; nn < 4; ++nn) {                                           \
        const int n = (nn + (RO)) & 3;                                         \
        _Pragma("unroll")                                                      \
        for (int rr = 0; rr < 16; ++rr) {                                      \
            const int r = (rr + 4 * (RO)) & 15;                                \
            const int row = rbase + (r & 3) + 8 * (r >> 2);                    \
            atomicAdd(&Gt[row * 128 + n * 32 + lm], acc[n][r]);                \
        }                                                                      \
    }
    switch (c & 3) {
        case 0: PUBROT(0); break;
        case 1: PUBROT(1); break;
        case 2: PUBROT(2); break;
        default: PUBROT(3); break;
    }
    if (t == 1) atomicAdd(&ws[WS_CS + tid], csum);

    __syncthreads();                           // drains vmcnt: adds complete
    if (tid == 0) {
        const unsigned d = __hip_atomic_fetch_add(
            &g_done, 1u, __ATOMIC_RELAXED, __HIP_MEMORY_SCOPE_AGENT);
        amFinal = ((d % GRID_BLKS) == GRID_BLKS - 1);
    }
    __syncthreads();
    if (!amFinal) return;                      // 47 blocks exit; no spinning

    // ---------------- final block: loss + sqrt ----------------
    // Atomic reads (atomicAdd(p,0)) execute at the coherent point -> see all
    // completed adds (round-3-proven pattern).
    float* muS = (float*)U;                    // U is dead; reuse LDS
    if (tid < WDIM)
        muS[tid] = atomicAdd(&ws[WS_CS + tid], 0.0f) * (1.0f / (float)BROWS);
    __syncthreads();

    float v = 0.f;
    #pragma unroll 8
    for (int e = tid; e < NT * TILE_ELEMS; e += 256) {
        const int tt = e >> 14, local = e & 16383;
        const int i = ((tt == 2) ? 128 : 0) + (local >> 7);
        const int j = ((tt == 0) ? 0 : 128) + (local & 127);
        const float g = atomicAdd(&ws[WS_G + e], 0.0f);
        const float diff = g * (1.0f / (float)BROWS) - muS[i] * muS[j]
                         - ((i == j) ? 1.0f : 0.0f);
        v += ((tt == 1) ? 2.0f : 1.0f) * diff * diff;
    }

    #pragma unroll
    for (int o = 32; o > 0; o >>= 1) v += __shfl_down(v, o, 64);
    if ((tid & 63) == 0) red[tid >> 6] = v;
    __syncthreads();
    if (tid == 0)
        out[0] = sqrtf(red[0] + red[1] + red[2] + red[3]);
}

// ---------------------------------------------------------------------- host
extern "C" void kernel_launch(void* const* d_in, const int* in_sizes, int n_in,
                              void* d_out, int out_size, void* d_ws, size_t ws_size,
                              hipStream_t stream) {
    const float* E = (const float*)d_in[0];
    // d_in[1] (label) unused by the reference math.
    float* out = (float*)d_out;
    float* ws = (float*)d_ws;

    corr_onepass<<<dim3(NT, CHUNKS), 256, 0, stream>>>(E, ws, out);
}

// Round 5
// 78.493 us; speedup vs baseline: 1.3592x; 1.3592x over previous
//
#include <hip/hip_runtime.h>
#include <math.h>

typedef unsigned int uint32;
typedef __bf16 bf16x8 __attribute__((ext_vector_type(8)));
typedef float f32x16 __attribute__((ext_vector_type(16)));

#define BROWS 8192
#define WDIM 256
#define NT 3              // 128x128 tile pairs: t0=(0,0), t1=(0,1), t2=(1,1)
#define CHUNKS 64         // 64 * 128 rows = 8192
#define RPB 128           // rows per block
#define TILE_ELEMS 16384
#define GRID_BLKS (NT * CHUNKS)   // 192 blocks; 64KB LDS -> 2/CU, all co-resident

// ws float layout — NO zeroing needed: every cell is fully overwritten with
// agent-scope atomic stores (write-through to coherent point) before any read.
// [0 .. 3145727]        G partials f32: bid*16384 + row*128 + col  (12.6 MB)
// [3145728 .. 3162111]  colsum f32 [c][256]
// [3162112 .. 3162303]  per-block loss [192]
#define WS_PART 0
#define WS_CS   (CHUNKS * NT * TILE_ELEMS)
#define WS_LOSS (WS_CS + CHUNKS * WDIM)

// Monotonic generation counters (device globals: ws is re-poisoned every
// iteration). +GRID_BLKS per launch; target = next multiple -> no reset
// needed across graph replays (proven rounds 3/4).
__device__ unsigned g_done = 0;
__device__ unsigned g_fin  = 0;

__device__ __forceinline__ uint32 pack2bf(float lo, float hi) {
    uint32 a = __float_as_uint(lo), b = __float_as_uint(hi);
    a = (a + 0x7FFFu + ((a >> 16) & 1u)) >> 16;   // RNE fp32->bf16
    b = (b + 0x7FFFu + ((b >> 16) & 1u)) >> 16;
    return (a & 0xFFFFu) | (b << 16);
}
__device__ __forceinline__ float bflo(uint32 v) { return __uint_as_float(v << 16); }
__device__ __forceinline__ float bfhi(uint32 v) { return __uint_as_float(v & 0xFFFF0000u); }

// LDS layout: U[col][krp] (krp = k/2, 64 dwords per col), 16B-group XOR swizzle.
__device__ __forceinline__ int uswz(int col, int krp) {
    return col * 64 + ((((krp >> 2) ^ (col & 15)) << 2) | (krp & 3));
}

__device__ __forceinline__ void aput(float* p, float v) {
    __hip_atomic_store(p, v, __ATOMIC_RELAXED, __HIP_MEMORY_SCOPE_AGENT);
}
__device__ __forceinline__ float aget(const float* p) {
    return __hip_atomic_load(p, __ATOMIC_RELAXED, __HIP_MEMORY_SCOPE_AGENT);
}

__global__ __launch_bounds__(256)
void corr_onepass(const float* __restrict__ E, float* __restrict__ ws,
                  float* __restrict__ out) {
    __shared__ uint32 U[WDIM * 64];            // 64 KB
    __shared__ float red[4];
    __shared__ int amFinal;
    const int t = blockIdx.x, c = blockIdx.y;
    const int tid = threadIdx.x;
    const int bid = c * NT + t;

    // ---------------- phase A: load 128 E rows + cast to LDS ----------------
    const int ncg = (t == 1) ? 4 : 2;          // 64-col groups held in U
    const int gcol0 = (t == 2) ? 128 : 0;      // global col of U local col 0
    const int row0 = c * RPB;
    const int c4 = tid & 15, rp = tid >> 4;
    const int w = tid >> 6, l = tid & 63, lm = l & 31;
    const int bBase = (t == 1) ? 128 : 0;
    const int colA = w * 32 + lm;

#define ISSUE(CG, FA, FB) do {                                                 \
    const float* Eb_ = E + (size_t)row0 * WDIM + gcol0 + (CG) * 64;            \
    _Pragma("unroll")                                                          \
    for (int p = 0; p < 4; ++p) {                                              \
        const int r0_ = 2 * (rp + 16 * p);                                     \
        FA[p] = *(const float4*)(Eb_ + (size_t)r0_ * WDIM + c4 * 4);           \
        FB[p] = *(const float4*)(Eb_ + (size_t)(r0_ + 1) * WDIM + c4 * 4);     \
    }                                                                          \
} while (0)

#define WRITE(CG, FA, FB) do {                                                 \
    const int colb_ = (CG) * 64 + c4 * 4;                                      \
    _Pragma("unroll")                                                          \
    for (int p = 0; p < 4; ++p) {                                              \
        const int krp_ = rp + 16 * p;                                          \
        U[uswz(colb_ + 0, krp_)] = pack2bf(FA[p].x, FB[p].x);                  \
        U[uswz(colb_ + 1, krp_)] = pack2bf(FA[p].y, FB[p].y);                  \
        U[uswz(colb_ + 2, krp_)] = pack2bf(FA[p].z, FB[p].z);                  \
        U[uswz(colb_ + 3, krp_)] = pack2bf(FA[p].w, FB[p].w);                  \
    }                                                                          \
} while (0)

    // 2-deep register prefetch hides HBM latency under LDS writes.
    float4 Afa[4], Afb[4], Bfa[4], Bfb[4];
    ISSUE(0, Afa, Afb);
    for (int it = 0; it < ncg; it += 2) {
        ISSUE(it + 1, Bfa, Bfb);
        WRITE(it, Afa, Afb);
        if (it + 2 < ncg) ISSUE(it + 2, Afa, Afb);
        WRITE(it + 1, Bfa, Bfb);
    }
    __syncthreads();

    // colsum (t==1 blocks see all 256 cols). bf16-rounded, f32 accumulate.
    float csum = 0.f;
    if (t == 1) {
        #pragma unroll
        for (int g = 0; g < 16; ++g) {
            const uint4 v = *(const uint4*)&U[tid * 64 + ((g ^ (tid & 15)) << 2)];
            csum += bflo(v.x) + bfhi(v.x) + bflo(v.y) + bfhi(v.y)
                  + bflo(v.z) + bfhi(v.z) + bflo(v.w) + bfhi(v.w);
        }
    }

    // MFMA: wave w -> tile rows [32w,32w+32); local col = global - gcol0.
    f32x16 acc[4];
    #pragma unroll
    for (int n = 0; n < 4; ++n)
        #pragma unroll
        for (int r = 0; r < 16; ++r) acc[n][r] = 0.f;

    #pragma unroll
    for (int s8 = 0; s8 < 8; ++s8) {           // K = 128 = 8 steps of 16
        const int grp = 2 * s8 + (l >> 5);     // logical 16B group = k/8
        const bf16x8 a = *(const bf16x8*)&U[colA * 64 + ((grp ^ (colA & 15)) << 2)];
        #pragma unroll
        for (int n = 0; n < 4; ++n) {
            const int colB = bBase + n * 32 + lm;
            const bf16x8 b = *(const bf16x8*)&U[colB * 64 + ((grp ^ (colB & 15)) << 2)];
            acc[n] = __builtin_amdgcn_mfma_f32_32x32x16_bf16(a, b, acc[n], 0, 0, 0);
        }
    }

    // ---- publish fp32 partials: agent-scope atomic STORES (write-through,
    // fire-and-forget, no contention — each block owns its tile) ----
    // C/D layout (m74/m101): col = lane&31, row = (r&3)+8*(r>>2)+4*(lane>>5)
    float* Gp = ws + WS_PART + (size_t)bid * TILE_ELEMS;
    const int rbase = 32 * w + 4 * (l >> 5);
    #pragma unroll
    for (int n = 0; n < 4; ++n)
        #pragma unroll
        for (int r = 0; r < 16; ++r) {
            const int row = rbase + (r & 3) + 8 * (r >> 2);
            aput(&Gp[row * 128 + n * 32 + lm], acc[n][r]);
        }
    if (t == 1) aput(&ws[WS_CS + c * WDIM + tid], csum);

    // ---- fence-free grid barrier: vmcnt drain (via __syncthreads) orders
    // the stores at the coherent point before the counter add ----
    __syncthreads();
    if (tid == 0) {
        const unsigned d = __hip_atomic_fetch_add(
            &g_done, 1u, __ATOMIC_RELAXED, __HIP_MEMORY_SCOPE_AGENT);
        const unsigned target = d - (d % GRID_BLKS) + GRID_BLKS;
        while (__hip_atomic_load(&g_done, __ATOMIC_RELAXED,
                                 __HIP_MEMORY_SCOPE_AGENT) < target)
            __builtin_amdgcn_s_sleep(4);
    }
    __syncthreads();

    // ---------------- distributed tail: block bid -> 256 outputs ----------------
    float* muS = (float*)U;                    // U is dead; reuse LDS
    {
        float s = 0.f;
        #pragma unroll 8
        for (int cc = 0; cc < CHUNKS; ++cc) s += aget(&ws[WS_CS + cc * WDIM + tid]);
        muS[tid] = s * (1.0f / (float)BROWS);
    }
    __syncthreads();

    const int e = bid * 256 + tid;             // 0..49151, tt uniform per block
    const int tt = e >> 14, local = e & 16383;
    const int i = ((tt == 2) ? 128 : 0) + (local >> 7);
    const int j = ((tt == 0) ? 0 : 128) + (local & 127);

    float g = 0.f;
    #pragma unroll 8
    for (int cc = 0; cc < CHUNKS; ++cc)
        g += aget(&ws[WS_PART + ((size_t)cc * NT + tt) * TILE_ELEMS + local]);

    const float diff = g * (1.0f / (float)BROWS) - muS[i] * muS[j]
                     - ((i == j) ? 1.0f : 0.0f);
    float v = ((tt == 1) ? 2.0f : 1.0f) * diff * diff;

    #pragma unroll
    for (int o = 32; o > 0; o >>= 1) v += __shfl_down(v, o, 64);
    if ((tid & 63) == 0) red[tid >> 6] = v;
    __syncthreads();

    // per-block loss -> slot; elect the LAST arriver to gather (no spinning)
    if (tid == 0) aput(&ws[WS_LOSS + bid], red[0] + red[1] + red[2] + red[3]);
    __syncthreads();                           // drains tid0's store (vmcnt 0)
    if (tid == 0) {
        const unsigned d2 = __hip_atomic_fetch_add(
            &g_fin, 1u, __ATOMIC_RELAXED, __HIP_MEMORY_SCOPE_AGENT);
        amFinal = ((d2 % GRID_BLKS) == GRID_BLKS - 1);
    }
    __syncthreads();
    if (!amFinal) return;                      // 191 blocks exit immediately

    float lv = (tid < GRID_BLKS) ? aget(&ws[WS_LOSS + tid]) : 0.f;
    #pragma unroll
    for (int o = 32; o > 0; o >>= 1) lv += __shfl_down(lv, o, 64);
    if ((tid & 63) == 0) red[tid >> 6] = lv;
    __syncthreads();
    if (tid == 0)
        out[0] = sqrtf(red[0] + red[1] + red[2] + red[3]);
}

// ---------------------------------------------------------------------- host
extern "C" void kernel_launch(void* const* d_in, const int* in_sizes, int n_in,
                              void* d_out, int out_size, void* d_ws, size_t ws_size,
                              hipStream_t stream) {
    const float* E = (const float*)d_in[0];
    // d_in[1] (label) unused by the reference math.
    float* out = (float*)d_out;
    float* ws = (float*)d_ws;

    corr_onepass<<<dim3(NT, CHUNKS), 256, 0, stream>>>(E, ws, out);
}

// Round 6
// 75.968 us; speedup vs baseline: 1.4044x; 1.0332x over previous
//
#include <hip/hip_runtime.h>
#include <math.h>

typedef unsigned int uint32;
typedef __bf16 bf16x8 __attribute__((ext_vector_type(8)));
typedef float f32x16 __attribute__((ext_vector_type(16)));
typedef float f32x4  __attribute__((ext_vector_type(4)));

#define BROWS 8192
#define WDIM 256
#define NT 3              // 128x128 tile pairs: t0=(0,0), t1=(0,1), t2=(1,1)
#define CHUNKS 64         // 64 * 128 rows = 8192
#define RPB 128           // rows per block
#define TILE_ELEMS 16384
#define GRID_BLKS (NT * CHUNKS)   // 192 blocks; 64KB LDS -> co-resident

// ws float layout — NO zeroing needed: every cell fully overwritten with
// agent-scope atomic stores (write-through to coherent point) before any read.
// [0 .. 3145727]        G partials f32: bid*16384 + row*128 + col  (12.6 MB)
// [3145728 .. 3162111]  colsum f32 [c][256]
// [3162112 .. 3162303]  per-block loss [192]
#define WS_PART 0
#define WS_CS   (CHUNKS * NT * TILE_ELEMS)
#define WS_LOSS (WS_CS + CHUNKS * WDIM)

// Monotonic generation counters (device globals: ws is re-poisoned every
// iteration). +GRID_BLKS per launch; target = next multiple -> no reset
// needed across graph replays (proven rounds 3-5).
__device__ unsigned g_done = 0;
__device__ unsigned g_fin  = 0;

__device__ __forceinline__ uint32 pack2bf(float lo, float hi) {
    uint32 a = __float_as_uint(lo), b = __float_as_uint(hi);
    a = (a + 0x7FFFu + ((a >> 16) & 1u)) >> 16;   // RNE fp32->bf16
    b = (b + 0x7FFFu + ((b >> 16) & 1u)) >> 16;
    return (a & 0xFFFFu) | (b << 16);
}
__device__ __forceinline__ float bflo(uint32 v) { return __uint_as_float(v << 16); }
__device__ __forceinline__ float bfhi(uint32 v) { return __uint_as_float(v & 0xFFFF0000u); }

// LDS layout: U[col][krp] (krp = k/2, 64 dwords per col), 16B-group XOR swizzle.
__device__ __forceinline__ int uswz(int col, int krp) {
    return col * 64 + ((((krp >> 2) ^ (col & 15)) << 2) | (krp & 3));
}

__device__ __forceinline__ void aput(float* p, float v) {
    __hip_atomic_store(p, v, __ATOMIC_RELAXED, __HIP_MEMORY_SCOPE_AGENT);
}

// 8 coherent 16B loads in flight, ONE waitcnt. Same visibility path as
// __hip_atomic_load (sc0 sc1: bypass L0/L1/L2 to the coherent point) but
// pipelined — the atomic-load builtin emits waitcnt vmcnt(0) per op, which
// serialized rounds 3-5's tails (~500-600 cyc per 4B read).
#define LD8(G0,G1,G2,G3,M0,M1,M2,M3,PG0,PG1,PG2,PG3,PM0,PM1,PM2,PM3)         \
    asm volatile(                                                            \
        "global_load_dwordx4 %0, %8, off sc0 sc1\n\t"                        \
        "global_load_dwordx4 %1, %9, off sc0 sc1\n\t"                        \
        "global_load_dwordx4 %2, %10, off sc0 sc1\n\t"                       \
        "global_load_dwordx4 %3, %11, off sc0 sc1\n\t"                       \
        "global_load_dwordx4 %4, %12, off sc0 sc1\n\t"                       \
        "global_load_dwordx4 %5, %13, off sc0 sc1\n\t"                       \
        "global_load_dwordx4 %6, %14, off sc0 sc1\n\t"                       \
        "global_load_dwordx4 %7, %15, off sc0 sc1\n\t"                       \
        "s_waitcnt vmcnt(0)"                                                 \
        : "=&v"(G0),"=&v"(G1),"=&v"(G2),"=&v"(G3),                           \
          "=&v"(M0),"=&v"(M1),"=&v"(M2),"=&v"(M3)                            \
        : "v"(PG0),"v"(PG1),"v"(PG2),"v"(PG3),                               \
          "v"(PM0),"v"(PM1),"v"(PM2),"v"(PM3))

#define LD1(R0,P0)                                                           \
    asm volatile("global_load_dwordx4 %0, %1, off sc0 sc1\n\t"               \
                 "s_waitcnt vmcnt(0)" : "=&v"(R0) : "v"(P0))

__global__ __launch_bounds__(256)
void corr_onepass(const float* __restrict__ E, float* __restrict__ ws,
                  float* __restrict__ out) {
    __shared__ uint32 U[WDIM * 64];            // 64 KB
    __shared__ float red[4];
    __shared__ int amFinal;
    const int t = blockIdx.x, c = blockIdx.y;
    const int tid = threadIdx.x;
    const int bid = c * NT + t;

    // ---------------- phase A: load 128 E rows + cast to LDS ----------------
    const int ncg = (t == 1) ? 4 : 2;          // 64-col groups held in U
    const int gcol0 = (t == 2) ? 128 : 0;      // global col of U local col 0
    const int row0 = c * RPB;
    const int c4 = tid & 15, rp = tid >> 4;
    const int w = tid >> 6, l = tid & 63, lm = l & 31;
    const int bBase = (t == 1) ? 128 : 0;
    const int colA = w * 32 + lm;

#define ISSUE(CG, FA, FB) do {                                                 \
    const float* Eb_ = E + (size_t)row0 * WDIM + gcol0 + (CG) * 64;            \
    _Pragma("unroll")                                                          \
    for (int p = 0; p < 4; ++p) {                                              \
        const int r0_ = 2 * (rp + 16 * p);                                     \
        FA[p] = *(const float4*)(Eb_ + (size_t)r0_ * WDIM + c4 * 4);           \
        FB[p] = *(const float4*)(Eb_ + (size_t)(r0_ + 1) * WDIM + c4 * 4);     \
    }                                                                          \
} while (0)

#define WRITE(CG, FA, FB) do {                                                 \
    const int colb_ = (CG) * 64 + c4 * 4;                                      \
    _Pragma("unroll")                                                          \
    for (int p = 0; p < 4; ++p) {                                              \
        const int krp_ = rp + 16 * p;                                          \
        U[uswz(colb_ + 0, krp_)] = pack2bf(FA[p].x, FB[p].x);                  \
        U[uswz(colb_ + 1, krp_)] = pack2bf(FA[p].y, FB[p].y);                  \
        U[uswz(colb_ + 2, krp_)] = pack2bf(FA[p].z, FB[p].z);                  \
        U[uswz(colb_ + 3, krp_)] = pack2bf(FA[p].w, FB[p].w);                  \
    }                                                                          \
} while (0)

    // 2-deep register prefetch hides HBM latency under LDS writes.
    float4 Afa[4], Afb[4], Bfa[4], Bfb[4];
    ISSUE(0, Afa, Afb);
    for (int it = 0; it < ncg; it += 2) {
        ISSUE(it + 1, Bfa, Bfb);
        WRITE(it, Afa, Afb);
        if (it + 2 < ncg) ISSUE(it + 2, Afa, Afb);
        WRITE(it + 1, Bfa, Bfb);
    }
    __syncthreads();

    // colsum (t==1 blocks see all 256 cols). bf16-rounded, f32 accumulate.
    float csum = 0.f;
    if (t == 1) {
        #pragma unroll
        for (int g = 0; g < 16; ++g) {
            const uint4 v = *(const uint4*)&U[tid * 64 + ((g ^ (tid & 15)) << 2)];
            csum += bflo(v.x) + bfhi(v.x) + bflo(v.y) + bfhi(v.y)
                  + bflo(v.z) + bfhi(v.z) + bflo(v.w) + bfhi(v.w);
        }
    }

    // MFMA: wave w -> tile rows [32w,32w+32); local col = global - gcol0.
    f32x16 acc[4];
    #pragma unroll
    for (int n = 0; n < 4; ++n)
        #pragma unroll
        for (int r = 0; r < 16; ++r) acc[n][r] = 0.f;

    #pragma unroll
    for (int s8 = 0; s8 < 8; ++s8) {           // K = 128 = 8 steps of 16
        const int grp = 2 * s8 + (l >> 5);     // logical 16B group = k/8
        const bf16x8 a = *(const bf16x8*)&U[colA * 64 + ((grp ^ (colA & 15)) << 2)];
        #pragma unroll
        for (int n = 0; n < 4; ++n) {
            const int colB = bBase + n * 32 + lm;
            const bf16x8 b = *(const bf16x8*)&U[colB * 64 + ((grp ^ (colB & 15)) << 2)];
            acc[n] = __builtin_amdgcn_mfma_f32_32x32x16_bf16(a, b, acc[n], 0, 0, 0);
        }
    }

    // ---- publish fp32 partials: agent-scope atomic STORES (write-through,
    // fire-and-forget, no contention — each block owns its tile) ----
    // C/D layout (m74/m101): col = lane&31, row = (r&3)+8*(r>>2)+4*(lane>>5)
    float* Gp = ws + WS_PART + (size_t)bid * TILE_ELEMS;
    const int rbase = 32 * w + 4 * (l >> 5);
    #pragma unroll
    for (int n = 0; n < 4; ++n)
        #pragma unroll
        for (int r = 0; r < 16; ++r) {
            const int row = rbase + (r & 3) + 8 * (r >> 2);
            aput(&Gp[row * 128 + n * 32 + lm], acc[n][r]);
        }
    if (t == 1) aput(&ws[WS_CS + c * WDIM + tid], csum);

    // ---- fence-free grid barrier: vmcnt drain (via __syncthreads) orders
    // the stores at the coherent point before the counter add (r5-proven) ----
    __syncthreads();
    if (tid == 0) {
        const unsigned d = __hip_atomic_fetch_add(
            &g_done, 1u, __ATOMIC_RELAXED, __HIP_MEMORY_SCOPE_AGENT);
        const unsigned target = d - (d % GRID_BLKS) + GRID_BLKS;
        while (__hip_atomic_load(&g_done, __ATOMIC_RELAXED,
                                 __HIP_MEMORY_SCOPE_AGENT) < target)
            __builtin_amdgcn_s_sleep(4);
    }
    __syncthreads();

    // ------------- distributed tail: block bid -> 256 outputs -------------
    // Wave w strips chunks [16w,16w+16); lane l owns the contiguous 16B slice
    // [local0+4l, local0+4l+4) of the output tile. 8 coherent loads in
    // flight per waitcnt (4 gram + 4 colsum), 4 rounds total.
    const int e0 = bid * 256;
    const int tt = e0 >> 14, local0 = e0 & 16383;
    const float* baseG = ws + WS_PART + (size_t)tt * TILE_ELEMS + local0 + 4 * l;
    const float* baseM = ws + WS_CS + 4 * l;

    f32x4 ag = {0.f, 0.f, 0.f, 0.f}, am = {0.f, 0.f, 0.f, 0.f};
    #pragma unroll
    for (int k = 0; k < 16; k += 4) {
        const int cc = w * 16 + k;
        f32x4 g0, g1, g2, g3, m0, m1, m2, m3;
        LD8(g0, g1, g2, g3, m0, m1, m2, m3,
            (const f32x4*)(baseG + (size_t)(cc + 0) * (NT * TILE_ELEMS)),
            (const f32x4*)(baseG + (size_t)(cc + 1) * (NT * TILE_ELEMS)),
            (const f32x4*)(baseG + (size_t)(cc + 2) * (NT * TILE_ELEMS)),
            (const f32x4*)(baseG + (size_t)(cc + 3) * (NT * TILE_ELEMS)),
            (const f32x4*)(baseM + (cc + 0) * WDIM),
            (const f32x4*)(baseM + (cc + 1) * WDIM),
            (const f32x4*)(baseM + (cc + 2) * WDIM),
            (const f32x4*)(baseM + (cc + 3) * WDIM));
        ag += g0 + g1 + g2 + g3;
        am += m0 + m1 + m2 + m3;
    }

    // Cross-wave LDS reduce (U is dead; reuse it).
    float* redg = (float*)U;                   // [4][256]
    float* redm = redg + 1024;                 // [4][256]
    float* muS  = redg + 2048;                 // [256]
    #pragma unroll
    for (int i2 = 0; i2 < 4; ++i2) {
        redg[w * 256 + 4 * l + i2] = ag[i2];
        redm[w * 256 + 4 * l + i2] = am[i2];
    }
    __syncthreads();
    muS[tid] = (redm[tid] + redm[256 + tid] + redm[512 + tid] + redm[768 + tid])
             * (1.0f / (float)BROWS);
    __syncthreads();

    const float gsum = redg[tid] + redg[256 + tid] + redg[512 + tid] + redg[768 + tid];
    const int local = local0 + tid;
    const int i = ((tt == 2) ? 128 : 0) + (local >> 7);
    const int j = ((tt == 0) ? 0 : 128) + (local & 127);
    const float diff = gsum * (1.0f / (float)BROWS) - muS[i] * muS[j]
                     - ((i == j) ? 1.0f : 0.0f);
    float v = ((tt == 1) ? 2.0f : 1.0f) * diff * diff;

    #pragma unroll
    for (int o = 32; o > 0; o >>= 1) v += __shfl_down(v, o, 64);
    if ((tid & 63) == 0) red[tid >> 6] = v;
    __syncthreads();

    // per-block loss -> slot; elect the LAST arriver to gather (no spinning)
    if (tid == 0) aput(&ws[WS_LOSS + bid], red[0] + red[1] + red[2] + red[3]);
    __syncthreads();                           // drains tid0's store
    if (tid == 0) {
        const unsigned d2 = __hip_atomic_fetch_add(
            &g_fin, 1u, __ATOMIC_RELAXED, __HIP_MEMORY_SCOPE_AGENT);
        amFinal = ((d2 % GRID_BLKS) == GRID_BLKS - 1);
    }
    __syncthreads();
    if (!amFinal) return;                      // 191 blocks exit immediately

    // final gather: 48 lanes x one dwordx4 (was 192 serialized atomic loads)
    f32x4 lv4 = {0.f, 0.f, 0.f, 0.f};
    if (tid < 48) LD1(lv4, (const f32x4*)(ws + WS_LOSS + 4 * tid));
    if (tid < 64) {
        float lv = lv4[0] + lv4[1] + lv4[2] + lv4[3];
        #pragma unroll
        for (int o = 32; o > 0; o >>= 1) lv += __shfl_down(lv, o, 64);
        if (tid == 0) out[0] = sqrtf(lv);
    }
}

// ---------------------------------------------------------------------- host
extern "C" void kernel_launch(void* const* d_in, const int* in_sizes, int n_in,
                              void* d_out, int out_size, void* d_ws, size_t ws_size,
                              hipStream_t stream) {
    const float* E = (const float*)d_in[0];
    // d_in[1] (label) unused by the reference math.
    float* out = (float*)d_out;
    float* ws = (float*)d_ws;

    corr_onepass<<<dim3(NT, CHUNKS), 256, 0, stream>>>(E, ws, out);
}

// Round 7
// 72.975 us; speedup vs baseline: 1.4620x; 1.0410x over previous
//
#include <hip/hip_runtime.h>
#include <math.h>

typedef unsigned int uint32;
typedef unsigned short u16;
typedef __bf16 bf16x8 __attribute__((ext_vector_type(8)));
typedef float f32x16 __attribute__((ext_vector_type(16)));
typedef float f32x4  __attribute__((ext_vector_type(4)));

#define BROWS 8192
#define WDIM 256
#define NT 3              // 128x128 tile pairs: t0=(0,0), t1=(0,1), t2=(1,1)
#define CHUNKS 64         // 64 * 128 rows = 8192
#define RPB 128           // rows per block
#define TILE_ELEMS 16384
#define GRID_BLKS (NT * CHUNKS)   // 192 blocks; 64KB LDS -> co-resident

// ws layout — NO zeroing needed: every cell fully overwritten with coherent
// stores before any read.
// u16 view:  [0 .. 3145727]            gram partials bf16: ((c*NT)+t)*16384 + row*128 + col
//            [3145728 .. 3162111]      colsum bf16 [c][256]
// f32 view:  [1581056 .. 1581247]      per-block loss [192]
#define WS_CSB_U16 (CHUNKS * NT * TILE_ELEMS)      // 3145728 (u16 index)
#define WS_LOSS_F32 1581056                        // float index (16B-aligned)

// Monotonic generation counters (device globals: ws is re-poisoned every
// iteration). +GRID_BLKS per launch; target = next multiple -> no reset
// needed across graph replays (proven rounds 3-6).
__device__ unsigned g_done = 0;
__device__ unsigned g_fin  = 0;

__device__ __forceinline__ uint32 pack2bf(float lo, float hi) {
    uint32 a = __float_as_uint(lo), b = __float_as_uint(hi);
    a = (a + 0x7FFFu + ((a >> 16) & 1u)) >> 16;   // RNE fp32->bf16
    b = (b + 0x7FFFu + ((b >> 16) & 1u)) >> 16;
    return (a & 0xFFFFu) | (b << 16);
}
__device__ __forceinline__ uint32 f2bf(float x) {
    uint32 a = __float_as_uint(x);
    return (a + 0x7FFFu + ((a >> 16) & 1u)) >> 16;
}
__device__ __forceinline__ float bflo(uint32 v) { return __uint_as_float(v << 16); }
__device__ __forceinline__ float bfhi(uint32 v) { return __uint_as_float(v & 0xFFFF0000u); }
__device__ __forceinline__ float bf(u16 v) { return __uint_as_float(((uint32)v) << 16); }

// LDS layout: U[col][krp] (krp = k/2, 64 dwords per col), 16B-group XOR swizzle.
__device__ __forceinline__ int uswz(int col, int krp) {
    return col * 64 + ((((krp >> 2) ^ (col & 15)) << 2) | (krp & 3));
}

__device__ __forceinline__ void aputf(float* p, float v) {
    __hip_atomic_store(p, v, __ATOMIC_RELAXED, __HIP_MEMORY_SCOPE_AGENT);
}
// coherent bf16 store (write-through to coherent point, fire-and-forget)
__device__ __forceinline__ void aput16(u16* p, uint32 v) {
    asm volatile("global_store_short %0, %1, off sc0 sc1"
                 :: "v"(p), "v"(v) : "memory");
}

// 8 coherent 16B loads in flight, ONE waitcnt (round-6-proven pattern).
#define LD8(R0,R1,R2,R3,R4,R5,R6,R7,P0,P1,P2,P3,P4,P5,P6,P7)                 \
    asm volatile(                                                            \
        "global_load_dwordx4 %0, %8, off sc0 sc1\n\t"                        \
        "global_load_dwordx4 %1, %9, off sc0 sc1\n\t"                        \
        "global_load_dwordx4 %2, %10, off sc0 sc1\n\t"                       \
        "global_load_dwordx4 %3, %11, off sc0 sc1\n\t"                       \
        "global_load_dwordx4 %4, %12, off sc0 sc1\n\t"                       \
        "global_load_dwordx4 %5, %13, off sc0 sc1\n\t"                       \
        "global_load_dwordx4 %6, %14, off sc0 sc1\n\t"                       \
        "global_load_dwordx4 %7, %15, off sc0 sc1\n\t"                       \
        "s_waitcnt vmcnt(0)"                                                 \
        : "=&v"(R0),"=&v"(R1),"=&v"(R2),"=&v"(R3),                           \
          "=&v"(R4),"=&v"(R5),"=&v"(R6),"=&v"(R7)                            \
        : "v"(P0),"v"(P1),"v"(P2),"v"(P3),                                   \
          "v"(P4),"v"(P5),"v"(P6),"v"(P7))

#define LD1(R0,P0)                                                           \
    asm volatile("global_load_dwordx4 %0, %1, off sc0 sc1\n\t"               \
                 "s_waitcnt vmcnt(0)" : "=&v"(R0) : "v"(P0))

__global__ __launch_bounds__(256)
void corr_onepass(const float* __restrict__ E, float* __restrict__ ws,
                  float* __restrict__ out) {
    __shared__ uint32 U[WDIM * 64];            // 64 KB
    __shared__ float red[4];
    __shared__ int amFinal;
    const int t = blockIdx.x, c = blockIdx.y;
    const int tid = threadIdx.x;
    const int bid = c * NT + t;

    // ---------------- phase A: load 128 E rows + cast to LDS ----------------
    const int ncg = (t == 1) ? 4 : 2;          // 64-col groups held in U
    const int gcol0 = (t == 2) ? 128 : 0;      // global col of U local col 0
    const int row0 = c * RPB;
    const int c4 = tid & 15, rp = tid >> 4;
    const int w = tid >> 6, l = tid & 63, lm = l & 31;
    const int bBase = (t == 1) ? 128 : 0;
    const int colA = w * 32 + lm;

#define ISSUE(CG, FA, FB) do {                                                 \
    const float* Eb_ = E + (size_t)row0 * WDIM + gcol0 + (CG) * 64;            \
    _Pragma("unroll")                                                          \
    for (int p = 0; p < 4; ++p) {                                              \
        const int r0_ = 2 * (rp + 16 * p);                                     \
        FA[p] = *(const float4*)(Eb_ + (size_t)r0_ * WDIM + c4 * 4);           \
        FB[p] = *(const float4*)(Eb_ + (size_t)(r0_ + 1) * WDIM + c4 * 4);     \
    }                                                                          \
} while (0)

#define WRITE(CG, FA, FB) do {                                                 \
    const int colb_ = (CG) * 64 + c4 * 4;                                      \
    _Pragma("unroll")                                                          \
    for (int p = 0; p < 4; ++p) {                                              \
        const int krp_ = rp + 16 * p;                                          \
        U[uswz(colb_ + 0, krp_)] = pack2bf(FA[p].x, FB[p].x);                  \
        U[uswz(colb_ + 1, krp_)] = pack2bf(FA[p].y, FB[p].y);                  \
        U[uswz(colb_ + 2, krp_)] = pack2bf(FA[p].z, FB[p].z);                  \
        U[uswz(colb_ + 3, krp_)] = pack2bf(FA[p].w, FB[p].w);                  \
    }                                                                          \
} while (0)

    // 2-deep register prefetch hides HBM latency under LDS writes.
    float4 Afa[4], Afb[4], Bfa[4], Bfb[4];
    ISSUE(0, Afa, Afb);
    for (int it = 0; it < ncg; it += 2) {
        ISSUE(it + 1, Bfa, Bfb);
        WRITE(it, Afa, Afb);
        if (it + 2 < ncg) ISSUE(it + 2, Afa, Afb);
        WRITE(it + 1, Bfa, Bfb);
    }
    __syncthreads();

    // colsum (t==1 blocks see all 256 cols). bf16-rounded, f32 accumulate.
    float csum = 0.f;
    if (t == 1) {
        #pragma unroll
        for (int g = 0; g < 16; ++g) {
            const uint4 v = *(const uint4*)&U[tid * 64 + ((g ^ (tid & 15)) << 2)];
            csum += bflo(v.x) + bfhi(v.x) + bflo(v.y) + bfhi(v.y)
                  + bflo(v.z) + bfhi(v.z) + bflo(v.w) + bfhi(v.w);
        }
    }

    // MFMA: wave w -> tile rows [32w,32w+32); local col = global - gcol0.
    f32x16 acc[4];
    #pragma unroll
    for (int n = 0; n < 4; ++n)
        #pragma unroll
        for (int r = 0; r < 16; ++r) acc[n][r] = 0.f;

    #pragma unroll
    for (int s8 = 0; s8 < 8; ++s8) {           // K = 128 = 8 steps of 16
        const int grp = 2 * s8 + (l >> 5);     // logical 16B group = k/8
        const bf16x8 a = *(const bf16x8*)&U[colA * 64 + ((grp ^ (colA & 15)) << 2)];
        #pragma unroll
        for (int n = 0; n < 4; ++n) {
            const int colB = bBase + n * 32 + lm;
            const bf16x8 b = *(const bf16x8*)&U[colB * 64 + ((grp ^ (colB & 15)) << 2)];
            acc[n] = __builtin_amdgcn_mfma_f32_32x32x16_bf16(a, b, acc[n], 0, 0, 0);
        }
    }

    // ---- publish bf16 partials: coherent stores, row-major coalesced ----
    // C/D layout (m74/m101): col = lane&31, row = (r&3)+8*(r>>2)+4*(lane>>5)
    u16* part = (u16*)ws;
    u16* dst = part + ((size_t)bid) * TILE_ELEMS;
    const int rbase = 32 * w + 4 * (l >> 5);
    #pragma unroll
    for (int n = 0; n < 4; ++n)
        #pragma unroll
        for (int r = 0; r < 16; ++r) {
            const int row = rbase + (r & 3) + 8 * (r >> 2);
            aput16(&dst[row * 128 + n * 32 + lm], f2bf(acc[n][r]));
        }
    if (t == 1) aput16(&part[WS_CSB_U16 + c * WDIM + tid], f2bf(csum));

    // ---- fence-free grid barrier: explicit vmcnt drain + __syncthreads
    // orders the stores at the coherent point before the counter add ----
    asm volatile("s_waitcnt vmcnt(0)" ::: "memory");
    __syncthreads();
    if (tid == 0) {
        const unsigned d = __hip_atomic_fetch_add(
            &g_done, 1u, __ATOMIC_RELAXED, __HIP_MEMORY_SCOPE_AGENT);
        const unsigned target = d - (d % GRID_BLKS) + GRID_BLKS;
        while (__hip_atomic_load(&g_done, __ATOMIC_RELAXED,
                                 __HIP_MEMORY_SCOPE_AGENT) < target)
            __builtin_amdgcn_s_sleep(4);
    }
    __syncthreads();

    // ------------- distributed tail: block bid -> 256 outputs -------------
    // Thread (w, h=l>>5, q=l&31): chunks cc = w*16 + h*8 + k (k<8); slice of
    // 8 consecutive bf16 at [8q, 8q+8). 16 coherent loads in TWO LD8 batches.
    const int e0 = bid * 256;
    const int tt = e0 >> 14, local0 = e0 & 16383;
    const int h = l >> 5, q = l & 31;
    const int cc0 = w * 16 + h * 8;
    const u16* baseG = part + (size_t)tt * TILE_ELEMS + local0 + 8 * q;
    const u16* baseM = part + WS_CSB_U16 + 8 * q;

    uint4 g0, g1, g2, g3, g4, g5, g6, g7;
    uint4 m0, m1, m2, m3, m4, m5, m6, m7;
    LD8(g0, g1, g2, g3, g4, g5, g6, g7,
        (const uint4*)(baseG + (size_t)(cc0 + 0) * (NT * TILE_ELEMS)),
        (const uint4*)(baseG + (size_t)(cc0 + 1) * (NT * TILE_ELEMS)),
        (const uint4*)(baseG + (size_t)(cc0 + 2) * (NT * TILE_ELEMS)),
        (const uint4*)(baseG + (size_t)(cc0 + 3) * (NT * TILE_ELEMS)),
        (const uint4*)(baseG + (size_t)(cc0 + 4) * (NT * TILE_ELEMS)),
        (const uint4*)(baseG + (size_t)(cc0 + 5) * (NT * TILE_ELEMS)),
        (const uint4*)(baseG + (size_t)(cc0 + 6) * (NT * TILE_ELEMS)),
        (const uint4*)(baseG + (size_t)(cc0 + 7) * (NT * TILE_ELEMS)));
    LD8(m0, m1, m2, m3, m4, m5, m6, m7,
        (const uint4*)(baseM + (cc0 + 0) * WDIM),
        (const uint4*)(baseM + (cc0 + 1) * WDIM),
        (const uint4*)(baseM + (cc0 + 2) * WDIM),
        (const uint4*)(baseM + (cc0 + 3) * WDIM),
        (const uint4*)(baseM + (cc0 + 4) * WDIM),
        (const uint4*)(baseM + (cc0 + 5) * WDIM),
        (const uint4*)(baseM + (cc0 + 6) * WDIM),
        (const uint4*)(baseM + (cc0 + 7) * WDIM));

    float gs[8] = {0,0,0,0,0,0,0,0}, ms[8] = {0,0,0,0,0,0,0,0};
#define ACC8(S, V) do {                                                      \
    S[0] += bflo(V.x); S[1] += bfhi(V.x); S[2] += bflo(V.y); S[3] += bfhi(V.y);\
    S[4] += bflo(V.z); S[5] += bfhi(V.z); S[6] += bflo(V.w); S[7] += bfhi(V.w);\
} while (0)
    ACC8(gs, g0); ACC8(gs, g1); ACC8(gs, g2); ACC8(gs, g3);
    ACC8(gs, g4); ACC8(gs, g5); ACC8(gs, g6); ACC8(gs, g7);
    ACC8(ms, m0); ACC8(ms, m1); ACC8(ms, m2); ACC8(ms, m3);
    ACC8(ms, m4); ACC8(ms, m5); ACC8(ms, m6); ACC8(ms, m7);

    // Cross-group LDS reduce (U is dead; reuse it).
    float* redg = (float*)U;                   // [8][256]
    float* redm = redg + 2048;                 // [8][256]
    float* muS  = redg + 4096;                 // [256]
    const int grpi = w * 2 + h;
    #pragma unroll
    for (int j2 = 0; j2 < 8; ++j2) {
        redg[grpi * 256 + 8 * q + j2] = gs[j2];
        redm[grpi * 256 + 8 * q + j2] = ms[j2];
    }
    __syncthreads();
    {
        float s = 0.f;
        #pragma unroll
        for (int gg = 0; gg < 8; ++gg) s += redm[gg * 256 + tid];
        muS[tid] = s * (1.0f / (float)BROWS);
    }
    float gsum = 0.f;
    #pragma unroll
    for (int gg = 0; gg < 8; ++gg) gsum += redg[gg * 256 + tid];
    __syncthreads();

    const int local = local0 + tid;
    const int i = ((tt == 2) ? 128 : 0) + (local >> 7);
    const int j = ((tt == 0) ? 0 : 128) + (local & 127);
    const float diff = gsum * (1.0f / (float)BROWS) - muS[i] * muS[j]
                     - ((i == j) ? 1.0f : 0.0f);
    float v = ((tt == 1) ? 2.0f : 1.0f) * diff * diff;

    #pragma unroll
    for (int o = 32; o > 0; o >>= 1) v += __shfl_down(v, o, 64);
    if ((tid & 63) == 0) red[tid >> 6] = v;
    __syncthreads();

    // per-block loss -> slot; elect the LAST arriver to gather (no spinning)
    float* lossp = ws + WS_LOSS_F32;
    if (tid == 0) aputf(&lossp[bid], red[0] + red[1] + red[2] + red[3]);
    asm volatile("s_waitcnt vmcnt(0)" ::: "memory");
    __syncthreads();
    if (tid == 0) {
        const unsigned d2 = __hip_atomic_fetch_add(
            &g_fin, 1u, __ATOMIC_RELAXED, __HIP_MEMORY_SCOPE_AGENT);
        amFinal = ((d2 % GRID_BLKS) == GRID_BLKS - 1);
    }
    __syncthreads();
    if (!amFinal) return;                      // 191 blocks exit immediately

    // final gather: 48 lanes x one dwordx4 (round-6-proven)
    f32x4 lv4 = {0.f, 0.f, 0.f, 0.f};
    if (tid < 48) LD1(lv4, (const f32x4*)(lossp + 4 * tid));
    if (tid < 64) {
        float lv = lv4[0] + lv4[1] + lv4[2] + lv4[3];
        #pragma unroll
        for (int o = 32; o > 0; o >>= 1) lv += __shfl_down(lv, o, 64);
        if (tid == 0) out[0] = sqrtf(lv);
    }
}

// ---------------------------------------------------------------------- host
extern "C" void kernel_launch(void* const* d_in, const int* in_sizes, int n_in,
                              void* d_out, int out_size, void* d_ws, size_t ws_size,
                              hipStream_t stream) {
    const float* E = (const float*)d_in[0];
    // d_in[1] (label) unused by the reference math.
    float* out = (float*)d_out;
    float* ws = (float*)d_ws;

    corr_onepass<<<dim3(NT, CHUNKS), 256, 0, stream>>>(E, ws, out);
}

// Round 8
// 72.251 us; speedup vs baseline: 1.4766x; 1.0100x over previous
//
#include <hip/hip_runtime.h>
#include <math.h>

typedef unsigned int uint32;
typedef unsigned short u16;
typedef __bf16 bf16x8 __attribute__((ext_vector_type(8)));
typedef float f32x16 __attribute__((ext_vector_type(16)));
typedef float f32x4  __attribute__((ext_vector_type(4)));

#define BROWS 8192
#define WDIM 256
#define NT 3              // tiles t0=(0,0), t1=(0,1), t2=(1,1)
#define CHUNKS 64         // 64 * 128 rows = 8192
#define RPB 128
#define TILE_ELEMS 16384
#define GRID_BLKS 64      // 64 fused-triple blocks x 512 threads

// ws layout (u16 view) — NO zeroing: every cell overwritten with coherent
// stores before any read.
// [0 .. 3145727]        gram partials bf16: ((c*NT)+t)*16384 + row*128 + col
// [3145728 .. 3162111]  colsum bf16 [c][256]
// f32 view: [1581056 .. 1581119] per-block loss [64]
#define WS_CSB_U16 (CHUNKS * NT * TILE_ELEMS)
#define WS_LOSS_F32 1581056

// Monotonic generation counters (device globals; ws is re-poisoned every
// iteration). +GRID_BLKS per launch; target = next multiple -> no reset
// needed across graph replays (proven rounds 3-7).
__device__ unsigned g_done = 0;
__device__ unsigned g_fin  = 0;

__device__ __forceinline__ uint32 pack2bf(float lo, float hi) {
    uint32 a = __float_as_uint(lo), b = __float_as_uint(hi);
    a = (a + 0x7FFFu + ((a >> 16) & 1u)) >> 16;   // RNE fp32->bf16
    b = (b + 0x7FFFu + ((b >> 16) & 1u)) >> 16;
    return (a & 0xFFFFu) | (b << 16);
}
__device__ __forceinline__ uint32 f2bf(float x) {
    uint32 a = __float_as_uint(x);
    return (a + 0x7FFFu + ((a >> 16) & 1u)) >> 16;
}
__device__ __forceinline__ float bflo(uint32 v) { return __uint_as_float(v << 16); }
__device__ __forceinline__ float bfhi(uint32 v) { return __uint_as_float(v & 0xFFFF0000u); }

// LDS: U[col][krp] (krp=k/2, 64 dwords/col), 16B-group XOR swizzle (proven).
__device__ __forceinline__ int uswz(int col, int krp) {
    return col * 64 + ((((krp >> 2) ^ (col & 15)) << 2) | (krp & 3));
}

__device__ __forceinline__ void aputf(float* p, float v) {
    __hip_atomic_store(p, v, __ATOMIC_RELAXED, __HIP_MEMORY_SCOPE_AGENT);
}
__device__ __forceinline__ void aput16(u16* p, uint32 v) {
    asm volatile("global_store_short %0, %1, off sc0 sc1"
                 :: "v"(p), "v"(v) : "memory");
}

// 8 coherent 16B loads in flight, one waitcnt (round-6/7-proven).
#define LD8(R0,R1,R2,R3,R4,R5,R6,R7,P0,P1,P2,P3,P4,P5,P6,P7)                 \
    asm volatile(                                                            \
        "global_load_dwordx4 %0, %8, off sc0 sc1\n\t"                        \
        "global_load_dwordx4 %1, %9, off sc0 sc1\n\t"                        \
        "global_load_dwordx4 %2, %10, off sc0 sc1\n\t"                       \
        "global_load_dwordx4 %3, %11, off sc0 sc1\n\t"                       \
        "global_load_dwordx4 %4, %12, off sc0 sc1\n\t"                       \
        "global_load_dwordx4 %5, %13, off sc0 sc1\n\t"                       \
        "global_load_dwordx4 %6, %14, off sc0 sc1\n\t"                       \
        "global_load_dwordx4 %7, %15, off sc0 sc1\n\t"                       \
        "s_waitcnt vmcnt(0)"                                                 \
        : "=&v"(R0),"=&v"(R1),"=&v"(R2),"=&v"(R3),                           \
          "=&v"(R4),"=&v"(R5),"=&v"(R6),"=&v"(R7)                            \
        : "v"(P0),"v"(P1),"v"(P2),"v"(P3),                                   \
          "v"(P4),"v"(P5),"v"(P6),"v"(P7))

#define LD1(R0,P0)                                                           \
    asm volatile("global_load_dwordx4 %0, %1, off sc0 sc1\n\t"               \
                 "s_waitcnt vmcnt(0)" : "=&v"(R0) : "v"(P0))

#define ACC8(S, V) do {                                                      \
    S[0] += bflo(V.x); S[1] += bfhi(V.x); S[2] += bflo(V.y); S[3] += bfhi(V.y);\
    S[4] += bflo(V.z); S[5] += bfhi(V.z); S[6] += bflo(V.w); S[7] += bfhi(V.w);\
} while (0)

__global__ __launch_bounds__(512)
void corr_v8(const float* __restrict__ E, float* __restrict__ ws,
             float* __restrict__ out) {
    __shared__ uint32 U[WDIM * 64];            // 64 KB: 256 cols x 128 rows bf16
    __shared__ float red[8];
    __shared__ int amFinal;
    const int c = blockIdx.x;
    const int tid = threadIdx.x;
    u16* part = (u16*)ws;

    // -------- phase A: read 128 E rows x 256 cols ONCE, cast to LDS --------
    const int row0 = c * RPB;
    const int c4 = tid & 15, rp = tid >> 4;    // rp 0..31

#define ISSUE(CG, FA, FB) do {                                                 \
    const float* Eb_ = E + (size_t)row0 * WDIM + (CG) * 64;                    \
    _Pragma("unroll")                                                          \
    for (int p = 0; p < 2; ++p) {                                              \
        const int r0_ = 2 * (rp + 32 * p);                                     \
        FA[p] = *(const float4*)(Eb_ + (size_t)r0_ * WDIM + c4 * 4);           \
        FB[p] = *(const float4*)(Eb_ + (size_t)(r0_ + 1) * WDIM + c4 * 4);     \
    }                                                                          \
} while (0)

#define WRITE(CG, FA, FB) do {                                                 \
    const int colb_ = (CG) * 64 + c4 * 4;                                      \
    _Pragma("unroll")                                                          \
    for (int p = 0; p < 2; ++p) {                                              \
        const int krp_ = rp + 32 * p;                                          \
        U[uswz(colb_ + 0, krp_)] = pack2bf(FA[p].x, FB[p].x);                  \
        U[uswz(colb_ + 1, krp_)] = pack2bf(FA[p].y, FB[p].y);                  \
        U[uswz(colb_ + 2, krp_)] = pack2bf(FA[p].z, FB[p].z);                  \
        U[uswz(colb_ + 3, krp_)] = pack2bf(FA[p].w, FB[p].w);                  \
    }                                                                          \
} while (0)

    float4 Afa[2], Afb[2], Bfa[2], Bfb[2];     // 2-deep prefetch (proven)
    ISSUE(0, Afa, Afb);
    for (int it = 0; it < 4; it += 2) {
        ISSUE(it + 1, Bfa, Bfb);
        WRITE(it, Afa, Afb);
        if (it + 2 < 4) ISSUE(it + 2, Afa, Afb);
        WRITE(it + 1, Bfa, Bfb);
    }
    __syncthreads();

    // colsum (every block holds all 256 cols of its 128 rows).
    float csum = 0.f;
    if (tid < 256) {
        #pragma unroll
        for (int g = 0; g < 16; ++g) {
            const uint4 v = *(const uint4*)&U[tid * 64 + ((g ^ (tid & 15)) << 2)];
            csum += bflo(v.x) + bfhi(v.x) + bflo(v.y) + bfhi(v.y)
                  + bflo(v.z) + bfhi(v.z) + bflo(v.w) + bfhi(v.w);
        }
    }

    // -------- MFMA: 8 waves, 6 acc tiles each --------
    // waves 0-3: t0[n=0..3] + t1[cols 0-63]  (rows 32w)
    // waves 4-7: t2[n=0..3] + t1[cols 64-127] (rows 32(w-4))
    const int w8 = tid >> 6, l = tid & 63, lm = l & 31;
    const int rg = w8 & 3;
    const bool hiW = (w8 >= 4);
    const int colA2 = rg * 32 + lm;                       // A lo (t0 / t1 rows)
    const int colA1 = (hiW ? 128 : 0) + rg * 32 + lm;     // main A (t0 or t2)
    const int bOff = hiW ? 128 : 0;                       // main tile B base
    const int t1n0 = hiW ? 2 : 0;                         // t1 n-offset

    f32x16 accA[4], accB[2];
    #pragma unroll
    for (int n = 0; n < 4; ++n)
        #pragma unroll
        for (int r = 0; r < 16; ++r) accA[n][r] = 0.f;
    #pragma unroll
    for (int m = 0; m < 2; ++m)
        #pragma unroll
        for (int r = 0; r < 16; ++r) accB[m][r] = 0.f;

#define FRAG(COL) (*(const bf16x8*)&U[(COL) * 64 + ((grp ^ ((COL) & 15)) << 2)])
    #pragma unroll
    for (int s8 = 0; s8 < 8; ++s8) {           // K = 128 rows, 8 steps of 16
        const int grp = 2 * s8 + (l >> 5);
        const bf16x8 aL = FRAG(colA2);
        bf16x8 aM;
        if (hiW) aM = FRAG(colA1); else aM = aL;   // wave-uniform branch
        #pragma unroll
        for (int n = 0; n < 4; ++n) {
            const bf16x8 b = FRAG(bOff + n * 32 + lm);
            accA[n] = __builtin_amdgcn_mfma_f32_32x32x16_bf16(aM, b, accA[n], 0, 0, 0);
        }
        #pragma unroll
        for (int m = 0; m < 2; ++m) {
            const bf16x8 b = FRAG(128 + (t1n0 + m) * 32 + lm);
            accB[m] = __builtin_amdgcn_mfma_f32_32x32x16_bf16(aL, b, accB[m], 0, 0, 0);
        }
    }

    // -------- publish bf16 partials (coherent fire-and-forget stores) -------
    // C/D layout (m74/m101): col = lane&31, row = (r&3)+8*(r>>2)+4*(lane>>5)
    const int tMain = hiW ? 2 : 0;
    u16* dstM = part + (size_t)(c * NT + tMain) * TILE_ELEMS;
    u16* dst1 = part + (size_t)(c * NT + 1) * TILE_ELEMS;
    const int rbase = 32 * rg + 4 * (l >> 5);
    #pragma unroll
    for (int n = 0; n < 4; ++n)
        #pragma unroll
        for (int r = 0; r < 16; ++r) {
            const int row = rbase + (r & 3) + 8 * (r >> 2);
            aput16(&dstM[row * 128 + n * 32 + lm], f2bf(accA[n][r]));
        }
    #pragma unroll
    for (int m = 0; m < 2; ++m)
        #pragma unroll
        for (int r = 0; r < 16; ++r) {
            const int row = rbase + (r & 3) + 8 * (r >> 2);
            aput16(&dst1[row * 128 + (t1n0 + m) * 32 + lm], f2bf(accB[m][r]));
        }
    if (tid < 256) aput16(&part[WS_CSB_U16 + c * WDIM + tid], f2bf(csum));

    // -------- fence-free grid barrier (64 arrivals; proven pattern) --------
    asm volatile("s_waitcnt vmcnt(0)" ::: "memory");
    __syncthreads();
    if (tid == 0) {
        const unsigned d = __hip_atomic_fetch_add(
            &g_done, 1u, __ATOMIC_RELAXED, __HIP_MEMORY_SCOPE_AGENT);
        const unsigned target = d - (d % GRID_BLKS) + GRID_BLKS;
        while (__hip_atomic_load(&g_done, __ATOMIC_RELAXED,
                                 __HIP_MEMORY_SCOPE_AGENT) < target)
            __builtin_amdgcn_s_sleep(4);
    }
    __syncthreads();

    // -------- distributed tail: block c -> 768 outputs (256 per tile) ------
    float* muS   = (float*)U;                  // [256]
    float* redm  = (float*)U + 256;            // [8][256]
    float* redgA = (float*)U + 2304;           // [8][256]
    float* redgB = (float*)U + 4352;           // [8][256]
    const int local0 = c * 256;

    // mu partial sums (tid<256), colsum slices batched (R7 m-pattern)
    if (tid < 256) {
        const int l2 = tid & 63, w2 = tid >> 6, h2 = l2 >> 5, q2 = l2 & 31;
        const int cc0 = w2 * 16 + h2 * 8, grpi = w2 * 2 + h2;
        const u16* baseM = part + WS_CSB_U16 + 8 * q2;
        uint4 m0, m1, m2, m3, m4, m5, m6, m7;
        LD8(m0, m1, m2, m3, m4, m5, m6, m7,
            (const uint4*)(baseM + (cc0 + 0) * WDIM),
            (const uint4*)(baseM + (cc0 + 1) * WDIM),
            (const uint4*)(baseM + (cc0 + 2) * WDIM),
            (const uint4*)(baseM + (cc0 + 3) * WDIM),
            (const uint4*)(baseM + (cc0 + 4) * WDIM),
            (const uint4*)(baseM + (cc0 + 5) * WDIM),
            (const uint4*)(baseM + (cc0 + 6) * WDIM),
            (const uint4*)(baseM + (cc0 + 7) * WDIM));
        float ms[8] = {0,0,0,0,0,0,0,0};
        ACC8(ms, m0); ACC8(ms, m1); ACC8(ms, m2); ACC8(ms, m3);
        ACC8(ms, m4); ACC8(ms, m5); ACC8(ms, m6); ACC8(ms, m7);
        #pragma unroll
        for (int j2 = 0; j2 < 8; ++j2) redm[grpi * 256 + 8 * q2 + j2] = ms[j2];
    }

    // gram pass 1: half h handles region tt=h (R7 g-pattern per 256 threads)
    const int hh = tid >> 8, tl = tid & 255;
    const int l3 = tl & 63, w3 = tl >> 6, h3 = l3 >> 5, q3 = l3 & 31;
    const int cc0g = w3 * 16 + h3 * 8, grpg = w3 * 2 + h3;
    {
        const u16* baseG = part + (size_t)hh * TILE_ELEMS + local0 + 8 * q3;
        uint4 g0, g1, g2, g3, g4, g5, g6, g7;
        LD8(g0, g1, g2, g3, g4, g5, g6, g7,
            (const uint4*)(baseG + (size_t)(cc0g + 0) * (NT * TILE_ELEMS)),
            (const uint4*)(baseG + (size_t)(cc0g + 1) * (NT * TILE_ELEMS)),
            (const uint4*)(baseG + (size_t)(cc0g + 2) * (NT * TILE_ELEMS)),
            (const uint4*)(baseG + (size_t)(cc0g + 3) * (NT * TILE_ELEMS)),
            (const uint4*)(baseG + (size_t)(cc0g + 4) * (NT * TILE_ELEMS)),
            (const uint4*)(baseG + (size_t)(cc0g + 5) * (NT * TILE_ELEMS)),
            (const uint4*)(baseG + (size_t)(cc0g + 6) * (NT * TILE_ELEMS)),
            (const uint4*)(baseG + (size_t)(cc0g + 7) * (NT * TILE_ELEMS)));
        float gs[8] = {0,0,0,0,0,0,0,0};
        ACC8(gs, g0); ACC8(gs, g1); ACC8(gs, g2); ACC8(gs, g3);
        ACC8(gs, g4); ACC8(gs, g5); ACC8(gs, g6); ACC8(gs, g7);
        float* rgp = hh ? redgB : redgA;
        #pragma unroll
        for (int j2 = 0; j2 < 8; ++j2) rgp[grpg * 256 + 8 * q3 + j2] = gs[j2];
    }
    __syncthreads();
    if (tid < 256) {
        float s = 0.f;
        #pragma unroll
        for (int gg = 0; gg < 8; ++gg) s += redm[gg * 256 + tid];
        muS[tid] = s * (1.0f / (float)BROWS);
    }
    __syncthreads();

    float v = 0.f;
    {   // finalize pass-1 output (tt=hh, local = local0+tl)
        const float* rgp = hh ? redgB : redgA;
        float gsum = 0.f;
        #pragma unroll
        for (int gg = 0; gg < 8; ++gg) gsum += rgp[gg * 256 + tl];
        const int local = local0 + tl;
        const int i = ((hh == 0) ? 0 : 0) + (local >> 7);          // tt=0/1: i in [0,128)
        const int j = ((hh == 0) ? 0 : 128) + (local & 127);
        const float diff = gsum * (1.0f / (float)BROWS) - muS[i] * muS[j]
                         - ((i == j) ? 1.0f : 0.0f);
        v += ((hh == 1) ? 2.0f : 1.0f) * diff * diff;
    }
    __syncthreads();                            // redgA free for pass 2

    // gram pass 2: tt=2 by tid<256
    if (tid < 256) {
        const u16* baseG = part + (size_t)2 * TILE_ELEMS + local0 + 8 * q3;
        uint4 g0, g1, g2, g3, g4, g5, g6, g7;
        LD8(g0, g1, g2, g3, g4, g5, g6, g7,
            (const uint4*)(baseG + (size_t)(cc0g + 0) * (NT * TILE_ELEMS)),
            (const uint4*)(baseG + (size_t)(cc0g + 1) * (NT * TILE_ELEMS)),
            (const uint4*)(baseG + (size_t)(cc0g + 2) * (NT * TILE_ELEMS)),
            (const uint4*)(baseG + (size_t)(cc0g + 3) * (NT * TILE_ELEMS)),
            (const uint4*)(baseG + (size_t)(cc0g + 4) * (NT * TILE_ELEMS)),
            (const uint4*)(baseG + (size_t)(cc0g + 5) * (NT * TILE_ELEMS)),
            (const uint4*)(baseG + (size_t)(cc0g + 6) * (NT * TILE_ELEMS)),
            (const uint4*)(baseG + (size_t)(cc0g + 7) * (NT * TILE_ELEMS)));
        float gs[8] = {0,0,0,0,0,0,0,0};
        ACC8(gs, g0); ACC8(gs, g1); ACC8(gs, g2); ACC8(gs, g3);
        ACC8(gs, g4); ACC8(gs, g5); ACC8(gs, g6); ACC8(gs, g7);
        #pragma unroll
        for (int j2 = 0; j2 < 8; ++j2) redgA[grpg * 256 + 8 * q3 + j2] = gs[j2];
    }
    __syncthreads();
    if (tid < 256) {
        float gsum = 0.f;
        #pragma unroll
        for (int gg = 0; gg < 8; ++gg) gsum += redgA[gg * 256 + tid];
        const int local = local0 + tid;
        const int i = 128 + (local >> 7);
        const int j = 128 + (local & 127);
        const float diff = gsum * (1.0f / (float)BROWS) - muS[i] * muS[j]
                         - ((i == j) ? 1.0f : 0.0f);
        v += diff * diff;
    }

    // block reduce (8 waves) -> per-block loss slot
    #pragma unroll
    for (int o = 32; o > 0; o >>= 1) v += __shfl_down(v, o, 64);
    if ((tid & 63) == 0) red[tid >> 6] = v;
    __syncthreads();
    float* lossp = ws + WS_LOSS_F32;
    if (tid == 0) {
        float bl = 0.f;
        #pragma unroll
        for (int k = 0; k < 8; ++k) bl += red[k];
        aputf(&lossp[c], bl);
    }
    asm volatile("s_waitcnt vmcnt(0)" ::: "memory");
    __syncthreads();
    if (tid == 0) {
        const unsigned d2 = __hip_atomic_fetch_add(
            &g_fin, 1u, __ATOMIC_RELAXED, __HIP_MEMORY_SCOPE_AGENT);
        amFinal = ((d2 % GRID_BLKS) == GRID_BLKS - 1);
    }
    __syncthreads();
    if (!amFinal) return;                      // 63 blocks exit immediately

    // final gather: 16 lanes x one dwordx4 over 64 per-block losses
    f32x4 lv4 = {0.f, 0.f, 0.f, 0.f};
    if (tid < 16) LD1(lv4, (const f32x4*)(lossp + 4 * tid));
    if (tid < 64) {
        float lv = lv4[0] + lv4[1] + lv4[2] + lv4[3];
        #pragma unroll
        for (int o = 32; o > 0; o >>= 1) lv += __shfl_down(lv, o, 64);
        if (tid == 0) out[0] = sqrtf(lv);
    }
}

// ---------------------------------------------------------------------- host
extern "C" void kernel_launch(void* const* d_in, const int* in_sizes, int n_in,
                              void* d_out, int out_size, void* d_ws, size_t ws_size,
                              hipStream_t stream) {
    const float* E = (const float*)d_in[0];
    // d_in[1] (label) unused by the reference math.
    float* out = (float*)d_out;
    float* ws = (float*)d_ws;

    corr_v8<<<dim3(GRID_BLKS), 512, 0, stream>>>(E, ws, out);
}